// Round 2
// baseline (264.114 us; speedup 1.0000x reference)
//
#include <hip/hip_runtime.h>
#include <hip/hip_bf16.h>

// Problem constants
#define Bb 2048
#define Tt 50
#define Vv 65
#define Ee 100
#define Hh 20
#define Dd 5

typedef __bf16 v8bf __attribute__((ext_vector_type(8)));
typedef float f32x4 __attribute__((ext_vector_type(4)));

__device__ __forceinline__ float bflo(unsigned u) { union { unsigned i; float f; } c; c.i = u << 16; return c.f; }
__device__ __forceinline__ float bfhi(unsigned u) { union { unsigned i; float f; } c; c.i = u & 0xffff0000u; return c.f; }

// ws layout (bytes)
#define WS_LOSS 0
#define WS_WKQV 1024                     // [320][128] bf16 (k rows pre-scaled by 10*log2e)
#define WS_WFF  (1024 + 81920)           // [128][128] bf16
#define WS_WLM  (1024 + 81920 + 32768)   // [80][128] bf16

#define XSTRIDE 136                      // x/attn/h row stride in bf16 elems (17*16B: aligned, 2-way-conflict only)

__global__ __launch_bounds__(256) void prep_kernel(
    const float* __restrict__ Wk, const float* __restrict__ Wq,
    const float* __restrict__ Wv, const float* __restrict__ Wff,
    const float* __restrict__ Wlm, char* __restrict__ ws)
{
    int g = blockIdx.x * 256 + threadIdx.x;
    if (g == 0) *(float*)(ws + WS_LOSS) = 0.f;
    __hip_bfloat16* wkqv = (__hip_bfloat16*)(ws + WS_WKQV);
    __hip_bfloat16* wff  = (__hip_bfloat16*)(ws + WS_WFF);
    __hip_bfloat16* wlm  = (__hip_bfloat16*)(ws + WS_WLM);
    if (g < 40960) {
        int n = g >> 7, e = g & 127;
        float v = 0.f;
        if (e < Ee) {
            if (n < 100)      v = Wk[n * Ee + e] * 14.4269504089f; // 10 * log2(e)
            else if (n < 200) v = Wq[(n - 100) * Ee + e];
            else if (n < 300) v = Wv[(n - 200) * Ee + e];
        }
        wkqv[g] = __float2bfloat16(v);
    } else if (g < 57344) {
        int gg = g - 40960; int n = gg >> 7, e = gg & 127;
        float v = (e < Ee && n < Ee) ? Wff[n * Ee + e] : 0.f;
        wff[gg] = __float2bfloat16(v);
    } else if (g < 67584) {
        int gg = g - 57344; int n = gg >> 7, e = gg & 127;
        float v = (e < Ee && n < Vv) ? Wlm[n * Ee + e] : 0.f;
        wlm[gg] = __float2bfloat16(v);
    }
}

__global__ __launch_bounds__(256) void gpt_main(
    const int* __restrict__ idx, const int* __restrict__ targets,
    const float* __restrict__ tok_emb, const float* __restrict__ pos_emb,
    const float* __restrict__ b_ff, const float* __restrict__ b_lm,
    const char* __restrict__ ws, float* __restrict__ out, float* __restrict__ loss_acc)
{
    // LDS: 17408 + 36000 + 4 = ~53.4 KB -> 3 blocks/CU
    __shared__ __attribute__((aligned(16))) __hip_bfloat16 xpad[64 * XSTRIDE]; // x, then attn, then h (zero-padded)
    __shared__ __attribute__((aligned(16))) __hip_bfloat16 kqv[18000];         // k@0, q@6000, v@12000 : [t][h][6]
    __shared__ float bsum;

    const int b    = blockIdx.x;
    const int tid  = threadIdx.x;
    const int wave = tid >> 6;
    const int lane = tid & 63;
    const int ln   = lane & 15;
    const int quad = lane >> 4;

    // ---- P1: x = tok_emb[idx] + pos_emb, zero-padded to [64][136] bf16 ----
    for (int i = tid; i < 64 * XSTRIDE; i += 256) {
        int r = i / XSTRIDE, c = i - (i / XSTRIDE) * XSTRIDE;
        float v = 0.f;
        if (r < Tt && c < Ee) {
            int tok = idx[b * Tt + r];
            v = tok_emb[tok * Ee + c] + pos_emb[r * Ee + c];
        }
        xpad[i] = __float2bfloat16(v);
    }
    __syncthreads();

    // ---- P2: kqv[50][300] = x @ Wkqv^T via MFMA 16x16x32 bf16 ----
    {
        const __hip_bfloat16* wkqv = (const __hip_bfloat16*)(ws + WS_WKQV);
        f32x4 acc[5][4];
#pragma unroll
        for (int i = 0; i < 5; ++i)
#pragma unroll
            for (int j = 0; j < 4; ++j) {
                f32x4 z = {0.f, 0.f, 0.f, 0.f};
                acc[i][j] = z;
            }
#pragma unroll
        for (int kt = 0; kt < 4; ++kt) {
            v8bf a[4];
#pragma unroll
            for (int mt = 0; mt < 4; ++mt)
                a[mt] = *(const v8bf*)&xpad[(mt * 16 + ln) * XSTRIDE + kt * 32 + quad * 8];
#pragma unroll
            for (int nt = 0; nt < 5; ++nt) {
                v8bf bfr = *(const v8bf*)&wkqv[(wave * 80 + nt * 16 + ln) * 128 + kt * 32 + quad * 8];
#pragma unroll
                for (int mt = 0; mt < 4; ++mt)
                    acc[nt][mt] = __builtin_amdgcn_mfma_f32_16x16x32_bf16(a[mt], bfr, acc[nt][mt], 0, 0, 0);
            }
        }
        // epilogue: C/D layout col(n)=lane&15, row(m)=quad*4+reg
#pragma unroll
        for (int nt = 0; nt < 5; ++nt) {
            int n = wave * 80 + nt * 16 + ln;
            if (n < 300) {
                int mat = n / 100;
                int jj  = n - mat * 100;
                int h   = jj / 5, d = jj - (jj / 5) * 5;
#pragma unroll
                for (int mt = 0; mt < 4; ++mt)
#pragma unroll
                    for (int r = 0; r < 4; ++r) {
                        int m = mt * 16 + quad * 4 + r;
                        if (m < Tt)
                            kqv[mat * 6000 + (m * 20 + h) * 6 + d] = __float2bfloat16(acc[nt][mt][r]);
                    }
            }
        }
    }
    __syncthreads();

    // ---- P3a: column-softmax denominators. softmax is over t (axis=2!), valid t>=s ----
    for (int it = tid; it < 1000; it += 256) {
        int s = it / 20, h = it - (it / 20) * 20;
        int qb = 6000 + (s * 20 + h) * 6;
        const unsigned* qp = (const unsigned*)&kqv[qb];
        unsigned u01 = qp[0], u23 = qp[1];
        float q0 = bflo(u01), q1 = bfhi(u01), q2 = bflo(u23), q3 = bfhi(u23);
        float q4 = __bfloat162float(kqv[qb + 4]);
        float sum = 0.f;
        for (int t = s; t < Tt; ++t) {
            int kb = (t * 20 + h) * 6;
            const unsigned* kp = (const unsigned*)&kqv[kb];
            unsigned k01 = kp[0], k23 = kp[1];
            float d01 = fmaf(bflo(k01), q0, bfhi(k01) * q1);
            float d23 = fmaf(bflo(k23), q2, bfhi(k23) * q3);
            float dot = fmaf(__bfloat162float(kqv[kb + 4]), q4, d01 + d23); // k pre-scaled by 10*log2e
            sum += __builtin_amdgcn_exp2f(dot);
        }
        kqv[12000 + (s * 20 + h) * 6 + 5] = __float2bfloat16(1.0f / sum);   // rdenom in v pad slot
    }
    __syncthreads();

    // ---- P3a2: fold rdenom into v ----
    for (int it = tid; it < 1000; it += 256) {
        int base = 12000 + it * 6;
        float rd = __bfloat162float(kqv[base + 5]);
#pragma unroll
        for (int d = 0; d < 5; ++d)
            kqv[base + d] = __float2bfloat16(__bfloat162float(kqv[base + d]) * rd);
    }
    __syncthreads();

    // ---- P3b: attn[t,d] = sum_{s<=t} exp2(k't.qs) * v'[s,d] -> xpad (bf16, MFMA-A layout) ----
    for (int it = tid; it < 1000; it += 256) {
        int t = it / 20, h = it - (it / 20) * 20;
        int kb = (t * 20 + h) * 6;
        const unsigned* kp = (const unsigned*)&kqv[kb];
        unsigned k01 = kp[0], k23 = kp[1];
        float k0 = bflo(k01), k1 = bfhi(k01), k2 = bflo(k23), k3 = bfhi(k23);
        float k4 = __bfloat162float(kqv[kb + 4]);
        float a0 = 0.f, a1 = 0.f, a2 = 0.f, a3 = 0.f, a4 = 0.f;
        for (int s = 0; s <= t; ++s) {
            int qb = 6000 + (s * 20 + h) * 6;
            const unsigned* qp = (const unsigned*)&kqv[qb];
            unsigned u01 = qp[0], u23 = qp[1];
            float d01 = fmaf(k0, bflo(u01), k1 * bfhi(u01));
            float d23 = fmaf(k2, bflo(u23), k3 * bfhi(u23));
            float dot = fmaf(k4, __bfloat162float(kqv[qb + 4]), d01 + d23);
            float p = __builtin_amdgcn_exp2f(dot);
            int vb = 12000 + (s * 20 + h) * 6;
            const unsigned* vp = (const unsigned*)&kqv[vb];
            unsigned v01 = vp[0], v23 = vp[1];
            a0 = fmaf(p, bflo(v01), a0);
            a1 = fmaf(p, bfhi(v01), a1);
            a2 = fmaf(p, bflo(v23), a2);
            a3 = fmaf(p, bfhi(v23), a3);
            a4 = fmaf(p, __bfloat162float(kqv[vb + 4]), a4);
        }
        int ab = t * XSTRIDE + h * 5;
        xpad[ab + 0] = __float2bfloat16(a0);
        xpad[ab + 1] = __float2bfloat16(a1);
        xpad[ab + 2] = __float2bfloat16(a2);
        xpad[ab + 3] = __float2bfloat16(a3);
        xpad[ab + 4] = __float2bfloat16(a4);
    }
    __syncthreads();

    // ---- P4: h = relu(attn @ Wff^T + b_ff) via MFMA, written back into xpad ----
    {
        const __hip_bfloat16* wff = (const __hip_bfloat16*)(ws + WS_WFF);
        f32x4 acc[2][4];
#pragma unroll
        for (int j = 0; j < 2; ++j)
#pragma unroll
            for (int mt = 0; mt < 4; ++mt) {
                f32x4 z = {0.f, 0.f, 0.f, 0.f};
                acc[j][mt] = z;
            }
#pragma unroll
        for (int kt = 0; kt < 4; ++kt) {
            v8bf a[4];
#pragma unroll
            for (int mt = 0; mt < 4; ++mt)
                a[mt] = *(const v8bf*)&xpad[(mt * 16 + ln) * XSTRIDE + kt * 32 + quad * 8];
#pragma unroll
            for (int j = 0; j < 2; ++j) {
                v8bf bfr = *(const v8bf*)&wff[((wave * 2 + j) * 16 + ln) * 128 + kt * 32 + quad * 8];
#pragma unroll
                for (int mt = 0; mt < 4; ++mt)
                    acc[j][mt] = __builtin_amdgcn_mfma_f32_16x16x32_bf16(a[mt], bfr, acc[j][mt], 0, 0, 0);
            }
        }
        __syncthreads();   // all attn reads done before overwriting xpad with h
#pragma unroll
        for (int j = 0; j < 2; ++j) {
            int n = wave * 32 + j * 16 + ln;
            if (n < Ee) {
                float bias = b_ff[n];
#pragma unroll
                for (int mt = 0; mt < 4; ++mt)
#pragma unroll
                    for (int r = 0; r < 4; ++r) {
                        int m = mt * 16 + quad * 4 + r;
                        if (m < Tt) {
                            float v = acc[j][mt][r] + bias;
                            xpad[m * XSTRIDE + n] = __float2bfloat16(v > 0.f ? v : 0.f);
                        }
                    }
            }
        }
    }
    __syncthreads();

    // ---- P5: logits = h @ Wlm^T + b_lm via MFMA; store fp32 global + fp32 LDS ----
    {
        const __hip_bfloat16* wlm = (const __hip_bfloat16*)(ws + WS_WLM);
        f32x4 acc[5];
#pragma unroll
        for (int nt = 0; nt < 5; ++nt) {
            f32x4 z = {0.f, 0.f, 0.f, 0.f};
            acc[nt] = z;
        }
#pragma unroll
        for (int kt = 0; kt < 4; ++kt) {
            v8bf a = *(const v8bf*)&xpad[(wave * 16 + ln) * XSTRIDE + kt * 32 + quad * 8];
#pragma unroll
            for (int nt = 0; nt < 5; ++nt) {
                v8bf bfr = *(const v8bf*)&wlm[(nt * 16 + ln) * 128 + kt * 32 + quad * 8];
                acc[nt] = __builtin_amdgcn_mfma_f32_16x16x32_bf16(a, bfr, acc[nt], 0, 0, 0);
            }
        }
        float* logits_lds = (float*)kqv;   // kqv is dead; 50*68*4 = 13.6 KB fits
#pragma unroll
        for (int nt = 0; nt < 5; ++nt) {
            int n = nt * 16 + ln;
            if (n < Vv) {
                float bias = b_lm[n];
#pragma unroll
                for (int r = 0; r < 4; ++r) {
                    int m = wave * 16 + quad * 4 + r;   // wave == m-tile
                    if (m < Tt) {
                        float v = acc[nt][r] + bias;
                        out[(b * Tt + m) * Vv + n] = v;
                        logits_lds[m * 68 + n] = v;
                    }
                }
            }
        }
    }
    if (tid == 0) bsum = 0.f;
    __syncthreads();

    // ---- P6: loss contributions ----
    if (tid < Tt) {
        const float* row = (const float*)kqv + tid * 68;
        float mx = row[0];
        for (int v = 1; v < Vv; ++v) mx = fmaxf(mx, row[v]);
        float sum = 0.f;
        for (int v = 0; v < Vv; ++v) sum += __builtin_amdgcn_exp2f((row[v] - mx) * 1.4426950408889634f);
        float lse = mx + 0.69314718055994531f * log2f(sum);
        int tgt = targets[b * Tt + tid];
        atomicAdd(&bsum, lse - row[tgt]);
    }
    __syncthreads();
    if (tid == 0) atomicAdd(loss_acc, bsum);
}

__global__ void finalize_kernel(const float* __restrict__ loss_acc, float* __restrict__ out)
{
    if (threadIdx.x == 0 && blockIdx.x == 0)
        out[Bb * Tt * Vv] = loss_acc[0] * (1.0f / (float)(Bb * Tt));
}

extern "C" void kernel_launch(void* const* d_in, const int* in_sizes, int n_in,
                              void* d_out, int out_size, void* d_ws, size_t ws_size,
                              hipStream_t stream)
{
    const int* idx     = (const int*)d_in[0];
    const int* targets = (const int*)d_in[1];
    const float* tok_emb = (const float*)d_in[2];
    const float* pos_emb = (const float*)d_in[3];
    const float* Wk  = (const float*)d_in[4];
    const float* Wq  = (const float*)d_in[5];
    const float* Wv  = (const float*)d_in[6];
    const float* Wff = (const float*)d_in[7];
    const float* bff = (const float*)d_in[8];
    const float* Wlm = (const float*)d_in[9];
    const float* blm = (const float*)d_in[10];
    float* out = (float*)d_out;
    char* ws = (char*)d_ws;
    float* loss_acc = (float*)(ws + WS_LOSS);

    hipLaunchKernelGGL(prep_kernel, dim3(264), dim3(256), 0, stream, Wk, Wq, Wv, Wff, Wlm, ws);
    hipLaunchKernelGGL(gpt_main, dim3(Bb), dim3(256), 0, stream,
                       idx, targets, tok_emb, pos_emb, bff, blm, (const char*)ws, out, loss_acc);
    hipLaunchKernelGGL(finalize_kernel, dim3(1), dim3(64), 0, stream, loss_acc, out);
}

// Round 3
// 226.373 us; speedup vs baseline: 1.1667x; 1.1667x over previous
//
#include <hip/hip_runtime.h>
#include <hip/hip_bf16.h>

// Problem constants
#define Bb 2048
#define Tt 50
#define Vv 65
#define Ee 100
#define Hh 20
#define Dd 5

typedef __bf16 v8bf __attribute__((ext_vector_type(8)));
typedef float f32x4 __attribute__((ext_vector_type(4)));

__device__ __forceinline__ float bflo(unsigned u) { union { unsigned i; float f; } c; c.i = u << 16; return c.f; }
__device__ __forceinline__ float bfhi(unsigned u) { union { unsigned i; float f; } c; c.i = u & 0xffff0000u; return c.f; }
__device__ __forceinline__ unsigned short bfbits(float f) {
    union { __hip_bfloat16 h; unsigned short s; } c;
    c.h = __float2bfloat16(f);
    return c.s;
}

// ws layout (bytes)
#define WS_LOSS 0                        // 4B loss accum + 4B done counter
#define WS_WKQV 1024                     // [320][128] bf16 (k rows pre-scaled by 10*log2e)
#define WS_WFF  (1024 + 81920)           // [128][128] bf16
#define WS_WLM  (1024 + 81920 + 32768)   // [80][128] bf16

#define XSTRIDE 136                      // x/attn/h row stride in bf16 elems (17*16B aligned)

__global__ __launch_bounds__(256) void prep_kernel(
    const float* __restrict__ Wk, const float* __restrict__ Wq,
    const float* __restrict__ Wv, const float* __restrict__ Wff,
    const float* __restrict__ Wlm, char* __restrict__ ws)
{
    int g = blockIdx.x * 256 + threadIdx.x;
    if (g == 0) { *(float*)(ws + WS_LOSS) = 0.f; *(unsigned*)(ws + WS_LOSS + 4) = 0u; }
    __hip_bfloat16* wkqv = (__hip_bfloat16*)(ws + WS_WKQV);
    __hip_bfloat16* wff  = (__hip_bfloat16*)(ws + WS_WFF);
    __hip_bfloat16* wlm  = (__hip_bfloat16*)(ws + WS_WLM);
    if (g < 40960) {
        int n = g >> 7, e = g & 127;
        float v = 0.f;
        if (e < Ee) {
            if (n < 100)      v = Wk[n * Ee + e] * 14.4269504089f; // 10 * log2(e)
            else if (n < 200) v = Wq[(n - 100) * Ee + e];
            else if (n < 300) v = Wv[(n - 200) * Ee + e];
        }
        wkqv[g] = __float2bfloat16(v);
    } else if (g < 57344) {
        int gg = g - 40960; int n = gg >> 7, e = gg & 127;
        float v = (e < Ee && n < Ee) ? Wff[n * Ee + e] : 0.f;
        wff[gg] = __float2bfloat16(v);
    } else {
        int gg = g - 57344; int n = gg >> 7, e = gg & 127;
        float v = (e < Ee && n < Vv) ? Wlm[n * Ee + e] : 0.f;
        wlm[gg] = __float2bfloat16(v);
    }
}

__global__ __launch_bounds__(512, 6) void gpt_main(
    const int* __restrict__ idx, const int* __restrict__ targets,
    const float* __restrict__ tok_emb, const float* __restrict__ pos_emb,
    const float* __restrict__ b_ff, const float* __restrict__ b_lm,
    const char* __restrict__ ws, float* __restrict__ out,
    float* __restrict__ loss_acc, unsigned* __restrict__ done_cnt)
{
    // LDS: 17408 + 36000 + 200 + 4 = ~53.6 KB -> 3 blocks/CU * 8 waves = 24 waves/CU
    __shared__ __attribute__((aligned(16))) __hip_bfloat16 xpad[64 * XSTRIDE]; // x -> attn -> h
    __shared__ __attribute__((aligned(16))) __hip_bfloat16 kqv[18000];         // k@0, q@6000, v@12000 : [t][h][6]
    __shared__ int tok_s[Tt];
    __shared__ float bsum;

    const int b    = blockIdx.x;
    const int tid  = threadIdx.x;
    const int wave = tid >> 6;
    const int ln   = tid & 15;
    const int quad = (tid >> 4) & 3;

    // ---- P1: stage idx, zero xpad, fill x = tok_emb[idx] + pos_emb (vectorized) ----
    if (tid < Tt) tok_s[tid] = idx[b * Tt + tid];
    if (tid == 0) bsum = 0.f;
    for (int i = tid; i < (64 * XSTRIDE) / 8; i += 512)
        ((uint4*)xpad)[i] = make_uint4(0u, 0u, 0u, 0u);
    __syncthreads();
    for (int i = tid; i < Tt * 25; i += 512) {
        int r = i / 25, c4 = (i - r * 25) * 4;
        const float4 te = *(const float4*)&tok_emb[tok_s[r] * Ee + c4];
        const float4 pe = *(const float4*)&pos_emb[r * Ee + c4];
        ushort4 o;
        o.x = bfbits(te.x + pe.x); o.y = bfbits(te.y + pe.y);
        o.z = bfbits(te.z + pe.z); o.w = bfbits(te.w + pe.w);
        *(ushort4*)&xpad[r * XSTRIDE + c4] = o;
    }
    __syncthreads();

    // ---- P2: kqv[50][300] = x @ Wkqv^T via MFMA 16x16x32 bf16 (8 waves: 2 m-split x 4 n-split) ----
    {
        const __hip_bfloat16* wkqv = (const __hip_bfloat16*)(ws + WS_WKQV);
        const int mw = wave & 1, nw = wave >> 1;   // nw in 0..3
        f32x4 acc[5][2];
#pragma unroll
        for (int ntl = 0; ntl < 5; ++ntl)
#pragma unroll
            for (int ml = 0; ml < 2; ++ml) {
                f32x4 z = {0.f, 0.f, 0.f, 0.f};
                acc[ntl][ml] = z;
            }
#pragma unroll
        for (int kt = 0; kt < 4; ++kt) {
            v8bf a0 = *(const v8bf*)&xpad[((mw * 2 + 0) * 16 + ln) * XSTRIDE + kt * 32 + quad * 8];
            v8bf a1 = *(const v8bf*)&xpad[((mw * 2 + 1) * 16 + ln) * XSTRIDE + kt * 32 + quad * 8];
#pragma unroll
            for (int ntl = 0; ntl < 5; ++ntl) {
                v8bf bfr = *(const v8bf*)&wkqv[((nw * 5 + ntl) * 16 + ln) * 128 + kt * 32 + quad * 8];
                acc[ntl][0] = __builtin_amdgcn_mfma_f32_16x16x32_bf16(a0, bfr, acc[ntl][0], 0, 0, 0);
                acc[ntl][1] = __builtin_amdgcn_mfma_f32_16x16x32_bf16(a1, bfr, acc[ntl][1], 0, 0, 0);
            }
        }
        // C/D layout: col(n)=lane&15, row(m)=quad*4+reg
#pragma unroll
        for (int ntl = 0; ntl < 5; ++ntl) {
            int n = (nw * 5 + ntl) * 16 + ln;
            if (n < 300) {
                int mat = n / 100;
                int jj  = n - mat * 100;
                int h   = jj / 5, d = jj - (jj / 5) * 5;
                int base = mat * 6000 + h * 6 + d;
#pragma unroll
                for (int ml = 0; ml < 2; ++ml)
#pragma unroll
                    for (int r = 0; r < 4; ++r) {
                        int m = (mw * 2 + ml) * 16 + quad * 4 + r;
                        if (m < Tt) kqv[base + m * 120] = __float2bfloat16(acc[ntl][ml][r]);
                    }
            }
        }
    }
    __syncthreads();

    // ---- P3a: column-softmax denominators (softmax over t, valid t>=s); pairwise s ----
    if (tid < 500) {
        const int i = tid / 20;
        const int h = tid - i * 20;
        const int s0 = 2 * i;
        const int qb = 6000 + (s0 * 20 + h) * 6;
        const unsigned* qp0 = (const unsigned*)&kqv[qb];
        const unsigned* qp1 = (const unsigned*)&kqv[qb + 120];
        unsigned a01 = qp0[0], a23 = qp0[1], a45 = qp0[2];
        unsigned c01 = qp1[0], c23 = qp1[1], c45 = qp1[2];
        float q00 = bflo(a01), q01 = bfhi(a01), q02 = bflo(a23), q03 = bfhi(a23), q04 = bflo(a45);
        float q10 = bflo(c01), q11 = bfhi(c01), q12 = bflo(c23), q13 = bfhi(c23), q14 = bflo(c45);
        float sum0, sum1 = 0.f;
        {   // t = s0 contributes to column s0 only
            const unsigned* kp = (const unsigned*)&kqv[(s0 * 20 + h) * 6];
            unsigned k01 = kp[0], k23 = kp[1], k45 = kp[2];
            float d01 = fmaf(bflo(k01), q00, bfhi(k01) * q01);
            float d23 = fmaf(bflo(k23), q02, bfhi(k23) * q03);
            sum0 = __builtin_amdgcn_exp2f(fmaf(bflo(k45), q04, d01 + d23));
        }
        for (int t = s0 + 1; t < Tt; ++t) {
            const unsigned* kp = (const unsigned*)&kqv[(t * 20 + h) * 6];
            unsigned k01 = kp[0], k23 = kp[1], k45 = kp[2];
            float k0 = bflo(k01), k1 = bfhi(k01), k2 = bflo(k23), k3 = bfhi(k23), k4 = bflo(k45);
            float d0 = fmaf(k0, q00, k1 * q01);
            float e0 = fmaf(k2, q02, k3 * q03);
            float dot0 = fmaf(k4, q04, d0 + e0);
            float d1 = fmaf(k0, q10, k1 * q11);
            float e1 = fmaf(k2, q12, k3 * q13);
            float dot1 = fmaf(k4, q14, d1 + e1);
            sum0 += __builtin_amdgcn_exp2f(dot0);
            sum1 += __builtin_amdgcn_exp2f(dot1);
        }
        kqv[12000 + (s0 * 20 + h) * 6 + 5]   = __float2bfloat16(1.0f / sum0);
        kqv[12000 + (s0 * 20 + h) * 6 + 125] = __float2bfloat16(1.0f / sum1);
    }
    __syncthreads();

    // ---- P3a2: fold rdenom into v ----
    for (int it = tid; it < 1000; it += 512) {
        int base = 12000 + it * 6;
        float rd = __bfloat162float(kqv[base + 5]);
#pragma unroll
        for (int d = 0; d < 5; ++d)
            kqv[base + d] = __float2bfloat16(__bfloat162float(kqv[base + d]) * rd);
    }
    __syncthreads();

    // ---- P3b: attn[t,d] = sum_{s<=t} exp2(k_t . q_s) * v'[s,d]; pairwise t ----
    if (tid < 500) {
        const int i = tid / 20;
        const int h = tid - i * 20;
        const int t0 = 2 * i;
        const int kb = (t0 * 20 + h) * 6;
        const unsigned* kp0 = (const unsigned*)&kqv[kb];
        const unsigned* kp1 = (const unsigned*)&kqv[kb + 120];
        unsigned a01 = kp0[0], a23 = kp0[1], a45 = kp0[2];
        unsigned c01 = kp1[0], c23 = kp1[1], c45 = kp1[2];
        float k00 = bflo(a01), k01v = bfhi(a01), k02 = bflo(a23), k03 = bfhi(a23), k04 = bflo(a45);
        float k10 = bflo(c01), k11 = bfhi(c01), k12 = bflo(c23), k13 = bfhi(c23), k14 = bflo(c45);
        float x0 = 0.f, x1 = 0.f, x2 = 0.f, x3 = 0.f, x4 = 0.f;
        float y0 = 0.f, y1 = 0.f, y2 = 0.f, y3 = 0.f, y4 = 0.f;
        const int qoff = 6000 + h * 6;
        const int voff = 12000 + h * 6;
        for (int s = 0; s <= t0; ++s) {
            const unsigned* qp = (const unsigned*)&kqv[qoff + s * 120];
            unsigned u01 = qp[0], u23 = qp[1], u45 = qp[2];
            float q0 = bflo(u01), q1 = bfhi(u01), q2 = bflo(u23), q3 = bfhi(u23), q4 = bflo(u45);
            float d0 = fmaf(k00, q0, k01v * q1);
            float e0 = fmaf(k02, q2, k03 * q3);
            float p0 = __builtin_amdgcn_exp2f(fmaf(k04, q4, d0 + e0));
            float d1 = fmaf(k10, q0, k11 * q1);
            float e1 = fmaf(k12, q2, k13 * q3);
            float p1 = __builtin_amdgcn_exp2f(fmaf(k14, q4, d1 + e1));
            const unsigned* vp = (const unsigned*)&kqv[voff + s * 120];
            unsigned v01 = vp[0], v23 = vp[1], v45 = vp[2];
            float w0 = bflo(v01), w1 = bfhi(v01), w2 = bflo(v23), w3 = bfhi(v23), w4 = bflo(v45);
            x0 = fmaf(p0, w0, x0); x1 = fmaf(p0, w1, x1); x2 = fmaf(p0, w2, x2);
            x3 = fmaf(p0, w3, x3); x4 = fmaf(p0, w4, x4);
            y0 = fmaf(p1, w0, y0); y1 = fmaf(p1, w1, y1); y2 = fmaf(p1, w2, y2);
            y3 = fmaf(p1, w3, y3); y4 = fmaf(p1, w4, y4);
        }
        {   // tail s = t0+1 contributes to row t1 only
            const int s = t0 + 1;
            const unsigned* qp = (const unsigned*)&kqv[qoff + s * 120];
            unsigned u01 = qp[0], u23 = qp[1], u45 = qp[2];
            float q0 = bflo(u01), q1 = bfhi(u01), q2 = bflo(u23), q3 = bfhi(u23), q4 = bflo(u45);
            float d1 = fmaf(k10, q0, k11 * q1);
            float e1 = fmaf(k12, q2, k13 * q3);
            float p1 = __builtin_amdgcn_exp2f(fmaf(k14, q4, d1 + e1));
            const unsigned* vp = (const unsigned*)&kqv[voff + s * 120];
            unsigned v01 = vp[0], v23 = vp[1], v45 = vp[2];
            y0 = fmaf(p1, bflo(v01), y0); y1 = fmaf(p1, bfhi(v01), y1);
            y2 = fmaf(p1, bflo(v23), y2); y3 = fmaf(p1, bfhi(v23), y3);
            y4 = fmaf(p1, bflo(v45), y4);
        }
        int ab0 = t0 * XSTRIDE + h * 5;
        xpad[ab0 + 0] = __float2bfloat16(x0); xpad[ab0 + 1] = __float2bfloat16(x1);
        xpad[ab0 + 2] = __float2bfloat16(x2); xpad[ab0 + 3] = __float2bfloat16(x3);
        xpad[ab0 + 4] = __float2bfloat16(x4);
        int ab1 = ab0 + XSTRIDE;
        xpad[ab1 + 0] = __float2bfloat16(y0); xpad[ab1 + 1] = __float2bfloat16(y1);
        xpad[ab1 + 2] = __float2bfloat16(y2); xpad[ab1 + 3] = __float2bfloat16(y3);
        xpad[ab1 + 4] = __float2bfloat16(y4);
    }
    __syncthreads();

    // ---- P4: h = relu(attn @ Wff^T + b_ff) via MFMA; waves 0..6 cover n-tiles ----
    {
        const __hip_bfloat16* wff = (const __hip_bfloat16*)(ws + WS_WFF);
        f32x4 facc[4];
#pragma unroll
        for (int mt = 0; mt < 4; ++mt) { f32x4 z = {0.f, 0.f, 0.f, 0.f}; facc[mt] = z; }
        if (wave < 7) {
#pragma unroll
            for (int kt = 0; kt < 4; ++kt) {
                v8bf bfr = *(const v8bf*)&wff[(wave * 16 + ln) * 128 + kt * 32 + quad * 8];
#pragma unroll
                for (int mt = 0; mt < 4; ++mt) {
                    v8bf a = *(const v8bf*)&xpad[(mt * 16 + ln) * XSTRIDE + kt * 32 + quad * 8];
                    facc[mt] = __builtin_amdgcn_mfma_f32_16x16x32_bf16(a, bfr, facc[mt], 0, 0, 0);
                }
            }
        }
        __syncthreads();   // all attn reads done before overwriting xpad with h
        if (wave < 7) {
            int n = wave * 16 + ln;
            if (n < Ee) {
                float bias = b_ff[n];
#pragma unroll
                for (int mt = 0; mt < 4; ++mt)
#pragma unroll
                    for (int r = 0; r < 4; ++r) {
                        int m = mt * 16 + quad * 4 + r;
                        if (m < Tt) {
                            float v = facc[mt][r] + bias;
                            xpad[m * XSTRIDE + n] = __float2bfloat16(v > 0.f ? v : 0.f);
                        }
                    }
            }
        }
    }
    __syncthreads();

    // ---- P5: logits = h @ Wlm^T + b_lm via MFMA; 20 (mt,nt) jobs over 8 waves ----
    {
        const __hip_bfloat16* wlm = (const __hip_bfloat16*)(ws + WS_WLM);
        float* logits_lds = (float*)kqv;   // kqv dead; 50*68*4 = 13.6 KB
        int jobs[3]; int nj = 2;
        jobs[0] = wave; jobs[1] = wave + 8; jobs[2] = 0;
        if (wave < 4) { jobs[2] = wave + 16; nj = 3; }
        for (int ji = 0; ji < nj; ++ji) {
            int j = jobs[ji];
            int mt = j / 5, nt = j - mt * 5;
            f32x4 acc = {0.f, 0.f, 0.f, 0.f};
#pragma unroll
            for (int kt = 0; kt < 4; ++kt) {
                v8bf a  = *(const v8bf*)&xpad[(mt * 16 + ln) * XSTRIDE + kt * 32 + quad * 8];
                v8bf bf = *(const v8bf*)&wlm[(nt * 16 + ln) * 128 + kt * 32 + quad * 8];
                acc = __builtin_amdgcn_mfma_f32_16x16x32_bf16(a, bf, acc, 0, 0, 0);
            }
            int n = nt * 16 + ln;
            if (n < Vv) {
                float bias = b_lm[n];
#pragma unroll
                for (int r = 0; r < 4; ++r) {
                    int m = mt * 16 + quad * 4 + r;
                    if (m < Tt) {
                        float v = acc[r] + bias;
                        out[(b * Tt + m) * Vv + n] = v;
                        logits_lds[m * 68 + n] = v;
                    }
                }
            }
        }
    }
    __syncthreads();

    // ---- P6: loss; 8 lanes per token row ----
    if (tid < 400) {
        int r = tid >> 3, lv = tid & 7;
        const float* row = (const float*)kqv + r * 68;
        float mx = -3.0e38f;
        for (int v = lv; v < Vv; v += 8) mx = fmaxf(mx, row[v]);
        mx = fmaxf(mx, __shfl_xor(mx, 1));
        mx = fmaxf(mx, __shfl_xor(mx, 2));
        mx = fmaxf(mx, __shfl_xor(mx, 4));
        float sum = 0.f;
        for (int v = lv; v < Vv; v += 8)
            sum += __builtin_amdgcn_exp2f((row[v] - mx) * 1.4426950408889634f);
        sum += __shfl_xor(sum, 1);
        sum += __shfl_xor(sum, 2);
        sum += __shfl_xor(sum, 4);
        if (lv == 0) {
            float lse = mx + 0.69314718055994531f * log2f(sum);
            int tgt = targets[b * Tt + r];
            atomicAdd(&bsum, lse - row[tgt]);
        }
    }
    __syncthreads();
    if (tid == 0) {
        atomicAdd(loss_acc, bsum);
        __threadfence();
        unsigned old = atomicAdd(done_cnt, 1u);
        if (old == (unsigned)(Bb - 1)) {       // last block finalizes the loss
            __threadfence();
            float total = atomicAdd(loss_acc, 0.0f);
            out[Bb * Tt * Vv] = total * (1.0f / (float)(Bb * Tt));
        }
    }
}

extern "C" void kernel_launch(void* const* d_in, const int* in_sizes, int n_in,
                              void* d_out, int out_size, void* d_ws, size_t ws_size,
                              hipStream_t stream)
{
    const int* idx     = (const int*)d_in[0];
    const int* targets = (const int*)d_in[1];
    const float* tok_emb = (const float*)d_in[2];
    const float* pos_emb = (const float*)d_in[3];
    const float* Wk  = (const float*)d_in[4];
    const float* Wq  = (const float*)d_in[5];
    const float* Wv  = (const float*)d_in[6];
    const float* Wff = (const float*)d_in[7];
    const float* bff = (const float*)d_in[8];
    const float* Wlm = (const float*)d_in[9];
    const float* blm = (const float*)d_in[10];
    float* out = (float*)d_out;
    char* ws = (char*)d_ws;
    float* loss_acc = (float*)(ws + WS_LOSS);
    unsigned* done_cnt = (unsigned*)(ws + WS_LOSS + 4);

    hipLaunchKernelGGL(prep_kernel, dim3(264), dim3(256), 0, stream, Wk, Wq, Wv, Wff, Wlm, ws);
    hipLaunchKernelGGL(gpt_main, dim3(Bb), dim3(512), 0, stream,
                       idx, targets, tok_emb, pos_emb, bff, blm, (const char*)ws, out,
                       loss_acc, done_cnt);
}